// Round 8
// baseline (306.727 us; speedup 1.0000x reference)
//
#include <hip/hip_runtime.h>
#include <math.h>

typedef __attribute__((ext_vector_type(8))) short bf16x8;
typedef __attribute__((ext_vector_type(16))) float f32x16;
typedef __attribute__((ext_vector_type(8))) unsigned short us8;

// ws layout (float offsets)
static constexpr size_t WS_WA   = 0;    // 64: wa1[32] ‖ wa2[32]
static constexpr size_t WS_C12  = 64;   // 2: b.a1, b.a2
static constexpr size_t WS_WMF  = 96;   // 1024 u16: stage-1 B frags [kap][l][e] = wm[t][f], t=16kap+8(l>>5)+e, f=l&31
static constexpr size_t WS_ADJF = 608;  // 1024 u16: stage-2 B frags (adj_n, same layout)

__device__ __forceinline__ unsigned short f2bf(float x){
    union { float f; unsigned u; } c; c.f = x;
    unsigned r = c.u + 0x7FFFu + ((c.u >> 16) & 1u);
    return (unsigned short)(r >> 16);
}
__device__ __forceinline__ unsigned pk2(float a, float b){
    return (unsigned)f2bf(a) | ((unsigned)f2bf(b) << 16);
}
__device__ __forceinline__ float bf2f(unsigned short v){
    return __uint_as_float(((unsigned)v) << 16);
}
__device__ __forceinline__ float elu(float x){ return x > 0.f ? x : __expf(x) - 1.0f; }
__device__ __forceinline__ float lrelu(float x){ return fmaxf(x, 0.2f * x); }

__global__ __launch_bounds__(1024) void k0_prep(const float* __restrict__ W_map,
    const float* __restrict__ b_map, const float* __restrict__ a_attn,
    const float* __restrict__ B_adj, float* __restrict__ ws)
{
    __shared__ float lds[1024];
    __shared__ float d12[32];
    int tid = threadIdx.x;
    int i = tid >> 5, j = tid & 31;
    float a = B_adj[tid] + (i == j ? 1.0f : 0.0f);
    lds[tid] = a; __syncthreads();
    for (int s = 512; s > 0; s >>= 1) { if (tid < s) lds[tid] = fmaxf(lds[tid], lds[tid + s]); __syncthreads(); }
    float mx = lds[0]; __syncthreads();
    lds[tid] = a; __syncthreads();
    for (int s = 512; s > 0; s >>= 1) { if (tid < s) lds[tid] = fminf(lds[tid], lds[tid + s]); __syncthreads(); }
    float mn = lds[0]; __syncthreads();
    lds[tid] = (a - mn) / (mx - mn); __syncthreads();
    if (tid < 32) {
        float s = 0.f;
        for (int jj = 0; jj < 32; ++jj) s += lds[tid * 32 + jj];
        d12[tid] = 1.0f / sqrtf(s);
    }
    __syncthreads();

    // frag-ordered constants: idx = kap*512 + l*8 + e
    {
        int kap = tid >> 9, rem = tid & 511, l = rem >> 3, e = rem & 7;
        int krow = 16 * kap + 8 * (l >> 5) + e;   // t (for wm) / i (for adj)
        int col  = l & 31;                        // f / i2
        ((unsigned short*)(ws + WS_WMF))[tid] = f2bf(W_map[krow * 32 + col]);
        float aij = B_adj[krow * 32 + col] + (krow == col ? 1.0f : 0.0f);
        float adjv = d12[krow] * ((aij - mn) / (mx - mn)) * d12[col];
        ((unsigned short*)(ws + WS_ADJF))[tid] = f2bf(adjv);
    }
    if (tid < 32) {
        float w1 = 0.f, w2 = 0.f;
        for (int f = 0; f < 32; ++f) {
            w1 += W_map[tid * 32 + f] * a_attn[f];
            w2 += W_map[tid * 32 + f] * a_attn[32 + f];
        }
        ws[WS_WA + tid] = w1; ws[WS_WA + 32 + tid] = w2;
    }
    if (tid == 0) {
        float c1 = 0.f, c2 = 0.f;
        for (int f = 0; f < 32; ++f) { c1 += b_map[f] * a_attn[f]; c2 += b_map[f] * a_attn[32 + f]; }
        ws[WS_C12] = c1; ws[WS_C12 + 1] = c2;
    }
}

// D(32x32 mfma, col=l&31) -> next-stage A/B frag (idx=l&31, k=16*KAP+8*hi+e).
template<int KAP>
__device__ __forceinline__ bf16x8 xform(const f32x16& d, int hi){
    unsigned b0 = pk2(d[8*KAP+0], d[8*KAP+1]);
    unsigned b1 = pk2(d[8*KAP+2], d[8*KAP+3]);
    unsigned b2 = pk2(d[8*KAP+4], d[8*KAP+5]);
    unsigned b3 = pk2(d[8*KAP+6], d[8*KAP+7]);
    unsigned pb0 = (unsigned)__shfl_xor((int)b0, 32, 64);
    unsigned pb1 = (unsigned)__shfl_xor((int)b1, 32, 64);
    unsigned pb2 = (unsigned)__shfl_xor((int)b2, 32, 64);
    unsigned pb3 = (unsigned)__shfl_xor((int)b3, 32, 64);
    union { unsigned u[4]; bf16x8 v; } t;
    t.u[0] = hi ? pb2 : b0;
    t.u[1] = hi ? pb3 : b1;
    t.u[2] = hi ? b2 : pb0;
    t.u[3] = hi ? b3 : pb1;
    return t.v;
}

// One block = HALF a (n,hh) row (32 sites). 76KB LDS + 64 VGPR -> 2 blocks/CU.
// Partner half's s1/s2 computed by streaming its h (no staging); rden full-row.
__global__ __launch_bounds__(1024, 8) void kfused(const float* __restrict__ hin,
    const float* __restrict__ b_map, const float* __restrict__ ws, float* __restrict__ out)
{
    __shared__ unsigned short hbf[32 * 1024];   // 64 KB: own half, frag order per site
    __shared__ unsigned short s1b[64 * 32];     // 4 KB bf16, FULL row
    __shared__ unsigned short s2b[64 * 32];     // 4 KB
    __shared__ float rdenL[1024];               // 4 KB
    __shared__ float waL[64];

    const int tid = threadIdx.x;
    const int wv = tid >> 6, l = tid & 63;
    const int c = l & 31, hi = l >> 5;
    const int blk = blockIdx.x;
    const int nh = blk >> 1, half = blk & 1;
    const int hh = nh & 63, n = nh >> 6;

    if (tid < 64) waL[tid] = ws[WS_WA + tid];
    const float c1 = ws[WS_C12], c2 = ws[WS_C12 + 1];
    const float bc = b_map[c];

    bf16x8 B1f[2], B2f[2];
    {
        const unsigned short* wmf = (const unsigned short*)(ws + WS_WMF);
        const unsigned short* adf = (const unsigned short*)(ws + WS_ADJF);
        B1f[0] = *(const bf16x8*)(wmf + l * 8);
        B1f[1] = *(const bf16x8*)(wmf + 512 + l * 8);
        B2f[0] = *(const bf16x8*)(adf + l * 8);
        B2f[1] = *(const bf16x8*)(adf + 512 + l * 8);
    }

    const float* hrow  = hin + (long)nh * 65536;
    const float* hhalf = hrow + half * 32768;

    // ---- phase A: stage own 32 sites -> bf16 frags (coalesced reads, b128 LDS writes) ----
    {
        const int v = tid & 31;
#pragma unroll
        for (int it = 0; it < 4; ++it) {
            const int gid = (it * 1024 + tid) >> 5;           // 0..127
            const int site = gid >> 2, kap = (gid >> 1) & 1, hw = gid & 1;
            const float* hp = hhalf + site * 1024 + (16 * kap + 8 * hw) * 32 + v;
            float x[8];
#pragma unroll
            for (int e = 0; e < 8; ++e) x[e] = hp[e * 32];
            union { unsigned u[4]; us8 v8; } pk;
            pk.u[0] = pk2(x[0], x[1]); pk.u[1] = pk2(x[2], x[3]);
            pk.u[2] = pk2(x[4], x[5]); pk.u[3] = pk2(x[6], x[7]);
            *(us8*)(hbf + site * 1024 + kap * 512 + (v + 32 * hw) * 8) = pk.v8;
        }
    }
    // ---- phase A3 (independent of LDS): other-half s1/s2 streamed from global ----
    float oa1, oa2; int osite;
    {
        osite = (1 - half) * 32 + (tid >> 5);                 // global w-index in row
        const int i = tid & 31;
        const float* hp = hrow + osite * 1024 + i;
        oa1 = c1; oa2 = c2;
#pragma unroll
        for (int t = 0; t < 32; ++t) {
            float x = hp[t * 32];
            oa1 = fmaf(x, waL[t], oa1);
            oa2 = fmaf(x, waL[32 + t], oa2);
        }
    }
    __syncthreads();

    // ---- phase A2: own-half s1/s2 from staged frags (2 sites/wave) ----
    {
        float wa1v[16], wa2v[16];
#pragma unroll
        for (int kk = 0; kk < 16; ++kk) {
            int t = 16 * (kk >> 3) + 8 * hi + (kk & 7);
            wa1v[kk] = waL[t]; wa2v[kk] = waL[32 + t];
        }
#pragma unroll
        for (int k = 0; k < 2; ++k) {
            int sloc = wv * 2 + k;
            const unsigned short* fp = hbf + sloc * 1024;
            bf16x8 f0 = *(const bf16x8*)(fp + l * 8);
            bf16x8 f1 = *(const bf16x8*)(fp + 512 + l * 8);
            float p1 = 0.f, p2 = 0.f;
#pragma unroll
            for (int e = 0; e < 8; ++e) {
                float x = bf2f((unsigned short)f0[e]);
                p1 = fmaf(x, wa1v[e], p1); p2 = fmaf(x, wa2v[e], p2);
            }
#pragma unroll
            for (int e = 0; e < 8; ++e) {
                float x = bf2f((unsigned short)f1[e]);
                p1 = fmaf(x, wa1v[8 + e], p1); p2 = fmaf(x, wa2v[8 + e], p2);
            }
            p1 += __shfl_xor(p1, 32, 64);
            p2 += __shfl_xor(p2, 32, 64);
            if (!hi) {
                int sg = half * 32 + sloc;
                s1b[sg * 32 + c] = f2bf(p1 + c1);
                s2b[sg * 32 + c] = f2bf(p2 + c2);
            }
        }
        const int i = tid & 31;
        s1b[osite * 32 + i] = f2bf(oa1);
        s2b[osite * 32 + i] = f2bf(oa2);
    }
    __syncthreads();

    // ---- phase B: rden[i][j] = 1/sum_w exp(lrelu(s1[w,i]+s2[w,j])) ----
    {
        int i = tid >> 5, j = tid & 31;
        float sum = 0.f;
#pragma unroll
        for (int w = 0; w < 64; ++w)
            sum += __expf(lrelu(bf2f(s1b[w * 32 + i]) + bf2f(s2b[w * 32 + j])));
        rdenL[tid] = 1.0f / sum;
    }
    __syncthreads();

    // ---- phase C: per wave 2 sites, 3 chained matmuls, NT stores ----
    const int hh5 = hh >> 5, f3 = hh & 31;
#pragma unroll 1
    for (int k = 0; k < 2; ++k) {
        const int ls = wv * 2 + k;
        const int gw = half * 32 + ls;
        const unsigned short* fp = hbf + ls * 1024;
        bf16x8 a10 = *(const bf16x8*)(fp + l * 8);
        bf16x8 a11 = *(const bf16x8*)(fp + 512 + l * 8);

        // stage 1: D1[j][f] = sum_t h[t][j] wm[t][f] + b[f]
        f32x16 d1;
#pragma unroll
        for (int r = 0; r < 16; ++r) d1[r] = bc;
        d1 = __builtin_amdgcn_mfma_f32_32x32x16_bf16(a10, B1f[0], d1, 0, 0, 0);
        d1 = __builtin_amdgcn_mfma_f32_32x32x16_bf16(a11, B1f[1], d1, 0, 0, 0);
        bf16x8 A3_0 = xform<0>(d1, hi);
        bf16x8 A3_1 = xform<1>(d1, hi);

        // stage 2: D2[j][i2] = sum_i attn[i,j] adj[i,i2]; attn in-register
        us8 r0 = *(const us8*)&s1b[gw * 32 + 8 * hi];
        us8 r1 = *(const us8*)&s1b[gw * 32 + 16 + 8 * hi];
        const float s2c = bf2f(s2b[gw * 32 + c]);
        float q[16];
#pragma unroll
        for (int e = 0; e < 4; ++e) {
            int i0 = 8 * hi + e, i1 = 8 * hi + 4 + e, i2i = 16 + 8 * hi + e, i3 = 16 + 8 * hi + 4 + e;
            q[e]      = __expf(lrelu(bf2f(r0[e])     + s2c)) * rdenL[i0 * 32 + c];
            q[4 + e]  = __expf(lrelu(bf2f(r0[4 + e]) + s2c)) * rdenL[i1 * 32 + c];
            q[8 + e]  = __expf(lrelu(bf2f(r1[e])     + s2c)) * rdenL[i2i * 32 + c];
            q[12 + e] = __expf(lrelu(bf2f(r1[4 + e]) + s2c)) * rdenL[i3 * 32 + c];
        }
        union { unsigned u[4]; bf16x8 v; } A2_0, A2_1;
        A2_0.u[0] = pk2(q[0], q[1]);   A2_0.u[1] = pk2(q[2], q[3]);
        A2_0.u[2] = pk2(q[4], q[5]);   A2_0.u[3] = pk2(q[6], q[7]);
        A2_1.u[0] = pk2(q[8], q[9]);   A2_1.u[1] = pk2(q[10], q[11]);
        A2_1.u[2] = pk2(q[12], q[13]); A2_1.u[3] = pk2(q[14], q[15]);

        f32x16 d2;
#pragma unroll
        for (int r = 0; r < 16; ++r) d2[r] = 0.f;
        d2 = __builtin_amdgcn_mfma_f32_32x32x16_bf16(A2_0.v, B2f[0], d2, 0, 0, 0);
        d2 = __builtin_amdgcn_mfma_f32_32x32x16_bf16(A2_1.v, B2f[1], d2, 0, 0, 0);
        bf16x8 B3_0 = xform<0>(d2, hi);
        bf16x8 B3_1 = xform<1>(d2, hi);

        // stage 3: D3[f][i2] = sum_j Wh[j][f] M[j][i2]
        f32x16 d3;
#pragma unroll
        for (int r = 0; r < 16; ++r) d3[r] = 0.f;
        d3 = __builtin_amdgcn_mfma_f32_32x32x16_bf16(A3_0, B3_0, d3, 0, 0, 0);
        d3 = __builtin_amdgcn_mfma_f32_32x32x16_bf16(A3_1, B3_1, d3, 0, 0, 0);

        float* ob = out + (((long)(n * 64 + gw) * 64) * 32 + f3) * 32 + c;
#pragma unroll
        for (int r = 0; r < 16; ++r) {
            int f = (r & 3) + 8 * (r >> 2) + 4 * hi;
            __builtin_nontemporal_store(elu(d3[r]), ob + (f * 2 + hh5) * 1024);
        }
    }
}

extern "C" void kernel_launch(void* const* d_in, const int* in_sizes, int n_in,
                              void* d_out, int out_size, void* d_ws, size_t ws_size,
                              hipStream_t stream) {
    (void)in_sizes; (void)n_in; (void)out_size; (void)ws_size;
    const float* hin    = (const float*)d_in[0];
    const float* W_map  = (const float*)d_in[1];
    const float* b_map  = (const float*)d_in[2];
    const float* a_attn = (const float*)d_in[3];
    const float* B_adj  = (const float*)d_in[4];
    float* out = (float*)d_out;
    float* ws  = (float*)d_ws;

    hipLaunchKernelGGL(k0_prep, dim3(1),    dim3(1024), 0, stream, W_map, b_map, a_attn, B_adj, ws);
    hipLaunchKernelGGL(kfused,  dim3(1024), dim3(1024), 0, stream, hin, b_map, ws, out);
}

// Round 9
// 87.138 us; speedup vs baseline: 3.5200x; 3.5200x over previous
//
#include <hip/hip_runtime.h>
#include <math.h>

typedef __attribute__((ext_vector_type(8))) short bf16x8;
typedef __attribute__((ext_vector_type(16))) float f32x16;
typedef __attribute__((ext_vector_type(8))) unsigned short us8;

// ws layout (float offsets)
static constexpr size_t WS_WA   = 0;    // 64: wa1[32] ‖ wa2[32]
static constexpr size_t WS_C12  = 64;   // 2: b.a1, b.a2
static constexpr size_t WS_WMF  = 96;   // 1024 u16: stage-1 B frags [kap][l][e] = wm[t][f], t=16kap+8(l>>5)+e, f=l&31
static constexpr size_t WS_ADJF = 608;  // 1024 u16: stage-2 B frags (adj_n, same layout)

__device__ __forceinline__ unsigned short f2bf(float x){
    union { float f; unsigned u; } c; c.f = x;
    unsigned r = c.u + 0x7FFFu + ((c.u >> 16) & 1u);
    return (unsigned short)(r >> 16);
}
__device__ __forceinline__ unsigned pk2(float a, float b){
    return (unsigned)f2bf(a) | ((unsigned)f2bf(b) << 16);
}
__device__ __forceinline__ float bf2f(unsigned short v){
    return __uint_as_float(((unsigned)v) << 16);
}
__device__ __forceinline__ float elu(float x){ return x > 0.f ? x : __expf(x) - 1.0f; }
__device__ __forceinline__ float lrelu(float x){ return fmaxf(x, 0.2f * x); }

__global__ __launch_bounds__(1024) void k0_prep(const float* __restrict__ W_map,
    const float* __restrict__ b_map, const float* __restrict__ a_attn,
    const float* __restrict__ B_adj, float* __restrict__ ws)
{
    __shared__ float lds[1024];
    __shared__ float d12[32];
    int tid = threadIdx.x;
    int i = tid >> 5, j = tid & 31;
    float a = B_adj[tid] + (i == j ? 1.0f : 0.0f);
    lds[tid] = a; __syncthreads();
    for (int s = 512; s > 0; s >>= 1) { if (tid < s) lds[tid] = fmaxf(lds[tid], lds[tid + s]); __syncthreads(); }
    float mx = lds[0]; __syncthreads();
    lds[tid] = a; __syncthreads();
    for (int s = 512; s > 0; s >>= 1) { if (tid < s) lds[tid] = fminf(lds[tid], lds[tid + s]); __syncthreads(); }
    float mn = lds[0]; __syncthreads();
    lds[tid] = (a - mn) / (mx - mn); __syncthreads();
    if (tid < 32) {
        float s = 0.f;
        for (int jj = 0; jj < 32; ++jj) s += lds[tid * 32 + jj];
        d12[tid] = 1.0f / sqrtf(s);
    }
    __syncthreads();

    // frag-ordered constants: idx = kap*512 + l*8 + e
    {
        int kap = tid >> 9, rem = tid & 511, l = rem >> 3, e = rem & 7;
        int krow = 16 * kap + 8 * (l >> 5) + e;   // t (for wm) / i (for adj)
        int col  = l & 31;                        // f / i2
        ((unsigned short*)(ws + WS_WMF))[tid] = f2bf(W_map[krow * 32 + col]);
        float aij = B_adj[krow * 32 + col] + (krow == col ? 1.0f : 0.0f);
        float adjv = d12[krow] * ((aij - mn) / (mx - mn)) * d12[col];
        ((unsigned short*)(ws + WS_ADJF))[tid] = f2bf(adjv);
    }
    if (tid < 32) {
        float w1 = 0.f, w2 = 0.f;
        for (int f = 0; f < 32; ++f) {
            w1 += W_map[tid * 32 + f] * a_attn[f];
            w2 += W_map[tid * 32 + f] * a_attn[32 + f];
        }
        ws[WS_WA + tid] = w1; ws[WS_WA + 32 + tid] = w2;
    }
    if (tid == 0) {
        float c1 = 0.f, c2 = 0.f;
        for (int f = 0; f < 32; ++f) { c1 += b_map[f] * a_attn[f]; c2 += b_map[f] * a_attn[32 + f]; }
        ws[WS_C12] = c1; ws[WS_C12 + 1] = c2;
    }
}

// D(32x32 mfma, col=l&31) -> next-stage A/B frag (idx=l&31, k=16*KAP+8*hi+e).
template<int KAP>
__device__ __forceinline__ bf16x8 xform(const f32x16& d, int hi){
    unsigned b0 = pk2(d[8*KAP+0], d[8*KAP+1]);
    unsigned b1 = pk2(d[8*KAP+2], d[8*KAP+3]);
    unsigned b2 = pk2(d[8*KAP+4], d[8*KAP+5]);
    unsigned b3 = pk2(d[8*KAP+6], d[8*KAP+7]);
    unsigned pb0 = (unsigned)__shfl_xor((int)b0, 32, 64);
    unsigned pb1 = (unsigned)__shfl_xor((int)b1, 32, 64);
    unsigned pb2 = (unsigned)__shfl_xor((int)b2, 32, 64);
    unsigned pb3 = (unsigned)__shfl_xor((int)b3, 32, 64);
    union { unsigned u[4]; bf16x8 v; } t;
    t.u[0] = hi ? pb2 : b0;
    t.u[1] = hi ? pb3 : b1;
    t.u[2] = hi ? b2 : pb0;
    t.u[3] = hi ? b3 : pb1;
    return t.v;
}

// One block = HALF a (n,hh) row (32 sites), 512 threads (8 waves, 4 sites/wave).
// 76KB LDS, natural VGPR (<=128 allows 2 blocks/CU = 16 waves/CU). Partner
// half's s1/s2 computed by streaming its h; rden full-row.
__global__ __launch_bounds__(512) void kfused(const float* __restrict__ hin,
    const float* __restrict__ b_map, const float* __restrict__ ws, float* __restrict__ out)
{
    __shared__ unsigned short hbf[32 * 1024];   // 64 KB: own half, frag order per site
    __shared__ unsigned short s1b[64 * 32];     // 4 KB bf16, FULL row
    __shared__ unsigned short s2b[64 * 32];     // 4 KB
    __shared__ float rdenL[1024];               // 4 KB
    __shared__ float waL[64];

    const int tid = threadIdx.x;
    const int wv = tid >> 6, l = tid & 63;
    const int c = l & 31, hi = l >> 5;
    // dispatch remap: halves of a row sit 8 apart in blockIdx -> same XCD (round-robin)
    const int bid = blockIdx.x;
    const int grp = bid >> 4, r = bid & 15;
    const int nh = grp * 8 + (r & 7), half = r >> 3;
    const int hh = nh & 63, n = nh >> 6;

    if (tid < 64) waL[tid] = ws[WS_WA + tid];
    const float c1 = ws[WS_C12], c2 = ws[WS_C12 + 1];
    const float bc = b_map[c];

    bf16x8 B1f[2], B2f[2];
    {
        const unsigned short* wmf = (const unsigned short*)(ws + WS_WMF);
        const unsigned short* adf = (const unsigned short*)(ws + WS_ADJF);
        B1f[0] = *(const bf16x8*)(wmf + l * 8);
        B1f[1] = *(const bf16x8*)(wmf + 512 + l * 8);
        B2f[0] = *(const bf16x8*)(adf + l * 8);
        B2f[1] = *(const bf16x8*)(adf + 512 + l * 8);
    }

    const float* hrow  = hin + (long)nh * 65536;
    const float* hhalf = hrow + half * 32768;

    // ---- phase A: stage own 32 sites -> bf16 frags (coalesced reads, b128 LDS writes) ----
    {
        const int v = tid & 31;
#pragma unroll
        for (int it = 0; it < 8; ++it) {
            const int gid = (it * 512 + tid) >> 5;            // 0..127
            const int site = gid >> 2, kap = (gid >> 1) & 1, hw = gid & 1;
            const float* hp = hhalf + site * 1024 + (16 * kap + 8 * hw) * 32 + v;
            float x[8];
#pragma unroll
            for (int e = 0; e < 8; ++e) x[e] = hp[e * 32];
            union { unsigned u[4]; us8 v8; } pk;
            pk.u[0] = pk2(x[0], x[1]); pk.u[1] = pk2(x[2], x[3]);
            pk.u[2] = pk2(x[4], x[5]); pk.u[3] = pk2(x[6], x[7]);
            *(us8*)(hbf + site * 1024 + kap * 512 + (v + 32 * hw) * 8) = pk.v8;
        }
    }
    // ---- phase A3 (register-only): partner-half s1/s2 streamed from global ----
    float oa1[2], oa2[2]; int osite[2];
    {
        const int i = tid & 31;
#pragma unroll
        for (int pass = 0; pass < 2; ++pass) {
            osite[pass] = (1 - half) * 32 + pass * 16 + (tid >> 5);
            const float* hp = hrow + osite[pass] * 1024 + i;
            float a1 = c1, a2 = c2;
#pragma unroll
            for (int t = 0; t < 32; ++t) {
                float x = hp[t * 32];
                a1 = fmaf(x, waL[t], a1);
                a2 = fmaf(x, waL[32 + t], a2);
            }
            oa1[pass] = a1; oa2[pass] = a2;
        }
    }
    __syncthreads();

    // ---- phase A2: own-half s1/s2 from staged frags (4 sites/wave) + partner writes ----
    {
        float wa1v[16], wa2v[16];
#pragma unroll
        for (int kk = 0; kk < 16; ++kk) {
            int t = 16 * (kk >> 3) + 8 * hi + (kk & 7);
            wa1v[kk] = waL[t]; wa2v[kk] = waL[32 + t];
        }
#pragma unroll
        for (int k = 0; k < 4; ++k) {
            int sloc = wv * 4 + k;
            const unsigned short* fp = hbf + sloc * 1024;
            bf16x8 f0 = *(const bf16x8*)(fp + l * 8);
            bf16x8 f1 = *(const bf16x8*)(fp + 512 + l * 8);
            float p1 = 0.f, p2 = 0.f;
#pragma unroll
            for (int e = 0; e < 8; ++e) {
                float x = bf2f((unsigned short)f0[e]);
                p1 = fmaf(x, wa1v[e], p1); p2 = fmaf(x, wa2v[e], p2);
            }
#pragma unroll
            for (int e = 0; e < 8; ++e) {
                float x = bf2f((unsigned short)f1[e]);
                p1 = fmaf(x, wa1v[8 + e], p1); p2 = fmaf(x, wa2v[8 + e], p2);
            }
            p1 += __shfl_xor(p1, 32, 64);
            p2 += __shfl_xor(p2, 32, 64);
            if (!hi) {
                int sg = half * 32 + sloc;
                s1b[sg * 32 + c] = f2bf(p1 + c1);
                s2b[sg * 32 + c] = f2bf(p2 + c2);
            }
        }
        const int i = tid & 31;
#pragma unroll
        for (int pass = 0; pass < 2; ++pass) {
            s1b[osite[pass] * 32 + i] = f2bf(oa1[pass]);
            s2b[osite[pass] * 32 + i] = f2bf(oa2[pass]);
        }
    }
    __syncthreads();

    // ---- phase B: rden[i][j] = 1/sum_w exp(lrelu(s1[w,i]+s2[w,j])) ----
    {
#pragma unroll
        for (int p = 0; p < 2; ++p) {
            int idx = p * 512 + tid;
            int i = idx >> 5, j = idx & 31;
            float sum = 0.f;
#pragma unroll
            for (int w = 0; w < 64; ++w)
                sum += __expf(lrelu(bf2f(s1b[w * 32 + i]) + bf2f(s2b[w * 32 + j])));
            rdenL[idx] = 1.0f / sum;
        }
    }
    __syncthreads();

    // ---- phase C: per wave 4 sites, 3 chained matmuls, NT stores ----
    const int hh5 = hh >> 5, f3 = hh & 31;
#pragma unroll 1
    for (int k = 0; k < 4; ++k) {
        const int ls = wv * 4 + k;
        const int gw = half * 32 + ls;
        const unsigned short* fp = hbf + ls * 1024;
        bf16x8 a10 = *(const bf16x8*)(fp + l * 8);
        bf16x8 a11 = *(const bf16x8*)(fp + 512 + l * 8);

        // stage 1: D1[j][f] = sum_t h[t][j] wm[t][f] + b[f]
        f32x16 d1;
#pragma unroll
        for (int r2 = 0; r2 < 16; ++r2) d1[r2] = bc;
        d1 = __builtin_amdgcn_mfma_f32_32x32x16_bf16(a10, B1f[0], d1, 0, 0, 0);
        d1 = __builtin_amdgcn_mfma_f32_32x32x16_bf16(a11, B1f[1], d1, 0, 0, 0);
        bf16x8 A3_0 = xform<0>(d1, hi);
        bf16x8 A3_1 = xform<1>(d1, hi);

        // stage 2: D2[j][i2] = sum_i attn[i,j] adj[i,i2]; attn in-register
        us8 r0 = *(const us8*)&s1b[gw * 32 + 8 * hi];
        us8 r1 = *(const us8*)&s1b[gw * 32 + 16 + 8 * hi];
        const float s2c = bf2f(s2b[gw * 32 + c]);
        float q[16];
#pragma unroll
        for (int e = 0; e < 4; ++e) {
            int i0 = 8 * hi + e, i1 = 8 * hi + 4 + e, i2i = 16 + 8 * hi + e, i3 = 16 + 8 * hi + 4 + e;
            q[e]      = __expf(lrelu(bf2f(r0[e])     + s2c)) * rdenL[i0 * 32 + c];
            q[4 + e]  = __expf(lrelu(bf2f(r0[4 + e]) + s2c)) * rdenL[i1 * 32 + c];
            q[8 + e]  = __expf(lrelu(bf2f(r1[e])     + s2c)) * rdenL[i2i * 32 + c];
            q[12 + e] = __expf(lrelu(bf2f(r1[4 + e]) + s2c)) * rdenL[i3 * 32 + c];
        }
        union { unsigned u[4]; bf16x8 v; } A2_0, A2_1;
        A2_0.u[0] = pk2(q[0], q[1]);   A2_0.u[1] = pk2(q[2], q[3]);
        A2_0.u[2] = pk2(q[4], q[5]);   A2_0.u[3] = pk2(q[6], q[7]);
        A2_1.u[0] = pk2(q[8], q[9]);   A2_1.u[1] = pk2(q[10], q[11]);
        A2_1.u[2] = pk2(q[12], q[13]); A2_1.u[3] = pk2(q[14], q[15]);

        f32x16 d2;
#pragma unroll
        for (int r2 = 0; r2 < 16; ++r2) d2[r2] = 0.f;
        d2 = __builtin_amdgcn_mfma_f32_32x32x16_bf16(A2_0.v, B2f[0], d2, 0, 0, 0);
        d2 = __builtin_amdgcn_mfma_f32_32x32x16_bf16(A2_1.v, B2f[1], d2, 0, 0, 0);
        bf16x8 B3_0 = xform<0>(d2, hi);
        bf16x8 B3_1 = xform<1>(d2, hi);

        // stage 3: D3[f][i2] = sum_j Wh[j][f] M[j][i2]
        f32x16 d3;
#pragma unroll
        for (int r2 = 0; r2 < 16; ++r2) d3[r2] = 0.f;
        d3 = __builtin_amdgcn_mfma_f32_32x32x16_bf16(A3_0, B3_0, d3, 0, 0, 0);
        d3 = __builtin_amdgcn_mfma_f32_32x32x16_bf16(A3_1, B3_1, d3, 0, 0, 0);

        float* ob = out + (((long)(n * 64 + gw) * 64) * 32 + f3) * 32 + c;
#pragma unroll
        for (int r2 = 0; r2 < 16; ++r2) {
            int f = (r2 & 3) + 8 * (r2 >> 2) + 4 * hi;
            __builtin_nontemporal_store(elu(d3[r2]), ob + (f * 2 + hh5) * 1024);
        }
    }
}

extern "C" void kernel_launch(void* const* d_in, const int* in_sizes, int n_in,
                              void* d_out, int out_size, void* d_ws, size_t ws_size,
                              hipStream_t stream) {
    (void)in_sizes; (void)n_in; (void)out_size; (void)ws_size;
    const float* hin    = (const float*)d_in[0];
    const float* W_map  = (const float*)d_in[1];
    const float* b_map  = (const float*)d_in[2];
    const float* a_attn = (const float*)d_in[3];
    const float* B_adj  = (const float*)d_in[4];
    float* out = (float*)d_out;
    float* ws  = (float*)d_ws;

    hipLaunchKernelGGL(k0_prep, dim3(1),    dim3(1024), 0, stream, W_map, b_map, a_attn, B_adj, ws);
    hipLaunchKernelGGL(kfused,  dim3(1024), dim3(512),  0, stream, hin, b_map, ws, out);
}

// Round 10
// 65.280 us; speedup vs baseline: 4.6986x; 1.3348x over previous
//
#include <hip/hip_runtime.h>
#include <math.h>

typedef __attribute__((ext_vector_type(8))) short bf16x8;
typedef __attribute__((ext_vector_type(16))) float f32x16;
typedef __attribute__((ext_vector_type(4))) float f32x4;
typedef __attribute__((ext_vector_type(8))) unsigned short us8;

// ws layout (float offsets)
static constexpr size_t WS_WA   = 0;    // 64: wa1[32] ‖ wa2[32]
static constexpr size_t WS_C12  = 64;   // 2: b.a1, b.a2
static constexpr size_t WS_WMF  = 96;   // 1024 u16: stage-1 B frags [kap][l][e] = wm[t][f], t=16kap+8(l>>5)+e, f=l&31
static constexpr size_t WS_ADJF = 608;  // 1024 u16: stage-2 B frags (adj_n, same layout)

__device__ __forceinline__ unsigned short f2bf(float x){
    union { float f; unsigned u; } c; c.f = x;
    unsigned r = c.u + 0x7FFFu + ((c.u >> 16) & 1u);
    return (unsigned short)(r >> 16);
}
__device__ __forceinline__ unsigned pk2(float a, float b){
    return (unsigned)f2bf(a) | ((unsigned)f2bf(b) << 16);
}
__device__ __forceinline__ float bf2f(unsigned short v){
    return __uint_as_float(((unsigned)v) << 16);
}
__device__ __forceinline__ float elu(float x){ return x > 0.f ? x : __expf(x) - 1.0f; }
__device__ __forceinline__ float lrelu(float x){ return fmaxf(x, 0.2f * x); }

__global__ __launch_bounds__(1024) void k0_prep(const float* __restrict__ W_map,
    const float* __restrict__ b_map, const float* __restrict__ a_attn,
    const float* __restrict__ B_adj, float* __restrict__ ws)
{
    __shared__ float lds[1024];
    __shared__ float d12[32];
    int tid = threadIdx.x;
    int i = tid >> 5, j = tid & 31;
    float a = B_adj[tid] + (i == j ? 1.0f : 0.0f);
    lds[tid] = a; __syncthreads();
    for (int s = 512; s > 0; s >>= 1) { if (tid < s) lds[tid] = fmaxf(lds[tid], lds[tid + s]); __syncthreads(); }
    float mx = lds[0]; __syncthreads();
    lds[tid] = a; __syncthreads();
    for (int s = 512; s > 0; s >>= 1) { if (tid < s) lds[tid] = fminf(lds[tid], lds[tid + s]); __syncthreads(); }
    float mn = lds[0]; __syncthreads();
    lds[tid] = (a - mn) / (mx - mn); __syncthreads();
    if (tid < 32) {
        float s = 0.f;
        for (int jj = 0; jj < 32; ++jj) s += lds[tid * 32 + jj];
        d12[tid] = 1.0f / sqrtf(s);
    }
    __syncthreads();

    // frag-ordered constants: idx = kap*512 + l*8 + e
    {
        int kap = tid >> 9, rem = tid & 511, l = rem >> 3, e = rem & 7;
        int krow = 16 * kap + 8 * (l >> 5) + e;   // t (for wm) / i (for adj)
        int col  = l & 31;                        // f / i2
        ((unsigned short*)(ws + WS_WMF))[tid] = f2bf(W_map[krow * 32 + col]);
        float aij = B_adj[krow * 32 + col] + (krow == col ? 1.0f : 0.0f);
        float adjv = d12[krow] * ((aij - mn) / (mx - mn)) * d12[col];
        ((unsigned short*)(ws + WS_ADJF))[tid] = f2bf(adjv);
    }
    if (tid < 32) {
        float w1 = 0.f, w2 = 0.f;
        for (int f = 0; f < 32; ++f) {
            w1 += W_map[tid * 32 + f] * a_attn[f];
            w2 += W_map[tid * 32 + f] * a_attn[32 + f];
        }
        ws[WS_WA + tid] = w1; ws[WS_WA + 32 + tid] = w2;
    }
    if (tid == 0) {
        float c1 = 0.f, c2 = 0.f;
        for (int f = 0; f < 32; ++f) { c1 += b_map[f] * a_attn[f]; c2 += b_map[f] * a_attn[32 + f]; }
        ws[WS_C12] = c1; ws[WS_C12 + 1] = c2;
    }
}

// D(32x32 mfma, col=l&31) -> next-stage A/B frag (idx=l&31, k=16*KAP+8*(l>>5)+e).
#if __has_builtin(__builtin_amdgcn_permlane32_swap)
typedef __attribute__((ext_vector_type(2))) unsigned int u32p;
template<int KAP>
__device__ __forceinline__ bf16x8 xform(const f32x16& d, int hi){
    (void)hi;
    unsigned b0 = pk2(d[8*KAP+0], d[8*KAP+1]);   // rows 0,1   (+4 if hi, +16KAP)
    unsigned b1 = pk2(d[8*KAP+2], d[8*KAP+3]);   // rows 2,3
    unsigned b2 = pk2(d[8*KAP+4], d[8*KAP+5]);   // rows 8,9
    unsigned b3 = pk2(d[8*KAP+6], d[8*KAP+7]);   // rows 10,11
    // swap(b0,b2): [0]=lo:own b0 | hi:partner b2 ; [1]=lo:partner b0 | hi:own b2
    u32p s02 = __builtin_amdgcn_permlane32_swap(b0, b2, false, false);
    u32p s13 = __builtin_amdgcn_permlane32_swap(b1, b3, false, false);
    union { unsigned u[4]; bf16x8 v; } t;
    t.u[0] = s02[0]; t.u[1] = s13[0]; t.u[2] = s02[1]; t.u[3] = s13[1];
    return t.v;
}
#else
template<int KAP>
__device__ __forceinline__ bf16x8 xform(const f32x16& d, int hi){
    unsigned b0 = pk2(d[8*KAP+0], d[8*KAP+1]);
    unsigned b1 = pk2(d[8*KAP+2], d[8*KAP+3]);
    unsigned b2 = pk2(d[8*KAP+4], d[8*KAP+5]);
    unsigned b3 = pk2(d[8*KAP+6], d[8*KAP+7]);
    unsigned pb0 = (unsigned)__shfl_xor((int)b0, 32, 64);
    unsigned pb1 = (unsigned)__shfl_xor((int)b1, 32, 64);
    unsigned pb2 = (unsigned)__shfl_xor((int)b2, 32, 64);
    unsigned pb3 = (unsigned)__shfl_xor((int)b3, 32, 64);
    union { unsigned u[4]; bf16x8 v; } t;
    t.u[0] = hi ? pb2 : b0;
    t.u[1] = hi ? pb3 : b1;
    t.u[2] = hi ? b2 : pb0;
    t.u[3] = hi ? b3 : pb1;
    return t.v;
}
#endif

// One block = one (n,hh) row. h staged to LDS (bf16 frag order) once, conflict-
// free gather; s1/s2/rden on-chip; 3 chained MFMA stages; NT stores only.
__global__ __launch_bounds__(1024, 4) void kfused(const float* __restrict__ hin,
    const float* __restrict__ b_map, const float* __restrict__ ws, float* __restrict__ out)
{
    __shared__ unsigned short hbf[64 * 1024];   // 128 KB: [s][kap][v+32hw][e]
    __shared__ float s1L[64 * 32];              // 8 KB  [w][i]
    __shared__ float s2L[64 * 32];              // 8 KB
    __shared__ float rdenL[1024];               // 4 KB  [i][j]
    __shared__ float waL[64];

    const int tid = threadIdx.x;
    const int wv = tid >> 6, l = tid & 63;
    const int c = l & 31, hi = l >> 5;
    const int nh = blockIdx.x;                  // n*64 + hh
    const int hh = nh & 63, n = nh >> 6;

    if (tid < 64) waL[tid] = ws[WS_WA + tid];
    const float c1 = ws[WS_C12], c2 = ws[WS_C12 + 1];
    const float bc = b_map[c];

    bf16x8 B1f[2], B2f[2];
    {
        const unsigned short* wmf = (const unsigned short*)(ws + WS_WMF);
        const unsigned short* adf = (const unsigned short*)(ws + WS_ADJF);
        B1f[0] = *(const bf16x8*)(wmf + l * 8);
        B1f[1] = *(const bf16x8*)(wmf + 512 + l * 8);
        B2f[0] = *(const bf16x8*)(adf + l * 8);
        B2f[1] = *(const bf16x8*)(adf + 512 + l * 8);
    }

    // ---- phase A: stage row -> hbf. Gather: 8 stride-32 scalar loads (128B
    // coalesced segments) -> one contiguous ds_write_b128. Zero conflicts. ----
    {
        const float* hrow = hin + (long)nh * 65536;
        const int v = tid & 31;
#pragma unroll
        for (int it = 0; it < 8; ++it) {
            const int gid = it * 32 + (tid >> 5);           // 0..255
            const int site = gid >> 2, kap = (gid >> 1) & 1, hw = gid & 1;
            const float* hp = hrow + site * 1024 + (16 * kap + 8 * hw) * 32 + v;
            float x[8];
#pragma unroll
            for (int e = 0; e < 8; ++e) x[e] = hp[e * 32];
            union { unsigned u[4]; us8 v8; } pk;
            pk.u[0] = pk2(x[0], x[1]); pk.u[1] = pk2(x[2], x[3]);
            pk.u[2] = pk2(x[4], x[5]); pk.u[3] = pk2(x[6], x[7]);
            *(us8*)(hbf + site * 1024 + kap * 512 + (v + 32 * hw) * 8) = pk.v8;
        }
    }
    __syncthreads();

    // ---- phase A2: s1/s2 per site from staged frags (4 sites/wave) ----
    {
        float wa1v[16], wa2v[16];
#pragma unroll
        for (int kk = 0; kk < 16; ++kk) {
            int t = 16 * (kk >> 3) + 8 * hi + (kk & 7);
            wa1v[kk] = waL[t]; wa2v[kk] = waL[32 + t];
        }
#pragma unroll
        for (int k = 0; k < 4; ++k) {
            int s = wv * 4 + k;
            const unsigned short* fp = hbf + s * 1024;
            bf16x8 f0 = *(const bf16x8*)(fp + l * 8);
            bf16x8 f1 = *(const bf16x8*)(fp + 512 + l * 8);
            float p1 = 0.f, p2 = 0.f;
#pragma unroll
            for (int e = 0; e < 8; ++e) {
                float x = bf2f((unsigned short)f0[e]);
                p1 = fmaf(x, wa1v[e], p1); p2 = fmaf(x, wa2v[e], p2);
            }
#pragma unroll
            for (int e = 0; e < 8; ++e) {
                float x = bf2f((unsigned short)f1[e]);
                p1 = fmaf(x, wa1v[8 + e], p1); p2 = fmaf(x, wa2v[8 + e], p2);
            }
            p1 += __shfl_xor(p1, 32, 64);
            p2 += __shfl_xor(p2, 32, 64);
            if (!hi) { s1L[s * 32 + c] = p1 + c1; s2L[s * 32 + c] = p2 + c2; }
        }
    }
    __syncthreads();

    // ---- phase B: rden[i][j] = 1/sum_w exp(lrelu(s1[w,i]+s2[w,j])) ----
    {
        int i = tid >> 5, j = tid & 31;
        float sum = 0.f;
#pragma unroll
        for (int w = 0; w < 64; ++w)
            sum += __expf(lrelu(s1L[w * 32 + i] + s2L[w * 32 + j]));
        rdenL[tid] = 1.0f / sum;
    }
    __syncthreads();

    // ---- phase C: per site, 3 chained 32x32 matmuls, NT stores ----
    const int hh5 = hh >> 5, f3 = hh & 31;
#pragma unroll 2
    for (int k = 0; k < 4; ++k) {
        const int s = wv * 4 + k;
        const unsigned short* fp = hbf + s * 1024;
        bf16x8 a10 = *(const bf16x8*)(fp + l * 8);
        bf16x8 a11 = *(const bf16x8*)(fp + 512 + l * 8);

        // stage 1: D1[j][f] = sum_t h[t][j] wm[t][f] + b[f]
        f32x16 d1;
#pragma unroll
        for (int r = 0; r < 16; ++r) d1[r] = bc;
        d1 = __builtin_amdgcn_mfma_f32_32x32x16_bf16(a10, B1f[0], d1, 0, 0, 0);
        d1 = __builtin_amdgcn_mfma_f32_32x32x16_bf16(a11, B1f[1], d1, 0, 0, 0);
        bf16x8 A3_0 = xform<0>(d1, hi);
        bf16x8 A3_1 = xform<1>(d1, hi);

        // stage 2: D2[j][i2] = sum_i attn[i,j] adj[i,i2]; attn built in-register
        const float s2c = s2L[s * 32 + c];
        f32x4 sa  = *(const f32x4*)&s1L[s * 32 + 8 * hi];
        f32x4 sb  = *(const f32x4*)&s1L[s * 32 + 8 * hi + 4];
        f32x4 sc_ = *(const f32x4*)&s1L[s * 32 + 16 + 8 * hi];
        f32x4 sd  = *(const f32x4*)&s1L[s * 32 + 16 + 8 * hi + 4];
        float q[16];
#pragma unroll
        for (int e = 0; e < 4; ++e) {
            int i0 = 8 * hi + e, i1 = 8 * hi + 4 + e, i2i = 16 + 8 * hi + e, i3 = 16 + 8 * hi + 4 + e;
            q[e]      = __expf(lrelu(sa[e] + s2c))  * rdenL[i0 * 32 + c];
            q[4 + e]  = __expf(lrelu(sb[e] + s2c))  * rdenL[i1 * 32 + c];
            q[8 + e]  = __expf(lrelu(sc_[e] + s2c)) * rdenL[i2i * 32 + c];
            q[12 + e] = __expf(lrelu(sd[e] + s2c))  * rdenL[i3 * 32 + c];
        }
        union { unsigned u[4]; bf16x8 v; } A2_0, A2_1;
        A2_0.u[0] = pk2(q[0], q[1]);   A2_0.u[1] = pk2(q[2], q[3]);
        A2_0.u[2] = pk2(q[4], q[5]);   A2_0.u[3] = pk2(q[6], q[7]);
        A2_1.u[0] = pk2(q[8], q[9]);   A2_1.u[1] = pk2(q[10], q[11]);
        A2_1.u[2] = pk2(q[12], q[13]); A2_1.u[3] = pk2(q[14], q[15]);

        f32x16 d2;
#pragma unroll
        for (int r = 0; r < 16; ++r) d2[r] = 0.f;
        d2 = __builtin_amdgcn_mfma_f32_32x32x16_bf16(A2_0.v, B2f[0], d2, 0, 0, 0);
        d2 = __builtin_amdgcn_mfma_f32_32x32x16_bf16(A2_1.v, B2f[1], d2, 0, 0, 0);
        bf16x8 B3_0 = xform<0>(d2, hi);
        bf16x8 B3_1 = xform<1>(d2, hi);

        // stage 3: D3[f][i2] = sum_j Wh[j][f] M[j][i2]
        f32x16 d3;
#pragma unroll
        for (int r = 0; r < 16; ++r) d3[r] = 0.f;
        d3 = __builtin_amdgcn_mfma_f32_32x32x16_bf16(A3_0, B3_0, d3, 0, 0, 0);
        d3 = __builtin_amdgcn_mfma_f32_32x32x16_bf16(A3_1, B3_1, d3, 0, 0, 0);

        // store: out[(((n*64+w)*64 + f*2+hh5)*32 + f3)*32 + c]
        float* ob = out + (((long)(n * 64 + s) * 64) * 32 + f3) * 32 + c;
#pragma unroll
        for (int r = 0; r < 16; ++r) {
            int f = (r & 3) + 8 * (r >> 2) + 4 * hi;
            __builtin_nontemporal_store(elu(d3[r]), ob + (f * 2 + hh5) * 1024);
        }
    }
}

extern "C" void kernel_launch(void* const* d_in, const int* in_sizes, int n_in,
                              void* d_out, int out_size, void* d_ws, size_t ws_size,
                              hipStream_t stream) {
    (void)in_sizes; (void)n_in; (void)out_size; (void)ws_size;
    const float* hin    = (const float*)d_in[0];
    const float* W_map  = (const float*)d_in[1];
    const float* b_map  = (const float*)d_in[2];
    const float* a_attn = (const float*)d_in[3];
    const float* B_adj  = (const float*)d_in[4];
    float* out = (float*)d_out;
    float* ws  = (float*)d_ws;

    hipLaunchKernelGGL(k0_prep, dim3(1),   dim3(1024), 0, stream, W_map, b_map, a_attn, B_adj, ws);
    hipLaunchKernelGGL(kfused,  dim3(512), dim3(1024), 0, stream, hin, b_map, ws, out);
}